// Round 8
// baseline (350.805 us; speedup 1.0000x reference)
//
#include <hip/hip_runtime.h>

typedef unsigned short u16;
typedef __attribute__((ext_vector_type(8))) __bf16 bf16x8;
typedef __attribute__((ext_vector_type(4))) float f32x4;
typedef __attribute__((ext_vector_type(4))) unsigned short u16x4;

#define DEV __device__ __forceinline__

DEV u16 f2bf(float f) {  // RTNE float->bf16
  unsigned u = __float_as_uint(f);
  u += 0x7fffu + ((u >> 16) & 1u);
  return (u16)(u >> 16);
}
DEV float bf2f(u16 u) { return __uint_as_float((unsigned)u << 16); }

// async global->LDS, 16B per lane. LDS dest is wave-uniform base + lane*16.
DEV void gl_lds16(const void* g, void* l) {
  __builtin_amdgcn_global_load_lds(
      (const __attribute__((address_space(1))) void*)(uintptr_t)g,
      (__attribute__((address_space(3))) void*)(unsigned)(uintptr_t)l, 16, 0, 0);
}

DEV float wave_sum64(float v) {
#pragma unroll
  for (int off = 32; off > 0; off >>= 1) v += __shfl_down(v, off);
  return v;  // lane 0 holds sum
}

// ---------------- LN body (shared by prep & proj_reduce_ln) ----------------
DEV void ln_body(const float4 v, const float* g, const float* be, u16* out_row, int t,
                 float* red) {
  const int w = t >> 6, L = t & 63;
  float s = v.x + v.y + v.z + v.w;
  s = wave_sum64(s);
  if (L == 0) red[w] = s;
  __syncthreads();
  const float mean = (red[0] + red[1] + red[2] + red[3]) * (1.0f / 1024.0f);
  const float dx = v.x - mean, dy = v.y - mean, dz = v.z - mean, dw = v.w - mean;
  float q = dx * dx + dy * dy + dz * dz + dw * dw;
  q = wave_sum64(q);
  if (L == 0) red[4 + w] = q;
  __syncthreads();
  const float var = (red[4] + red[5] + red[6] + red[7]) * (1.0f / 1024.0f);
  const float rs = rsqrtf(var + 1e-5f);
  const float4 gg = reinterpret_cast<const float4*>(g)[t];
  const float4 bb = reinterpret_cast<const float4*>(be)[t];
  ushort4 o;
  o.x = f2bf(dx * rs * gg.x + bb.x);
  o.y = f2bf(dy * rs * gg.y + bb.y);
  o.z = f2bf(dz * rs * gg.z + bb.z);
  o.w = f2bf(dw * rs * gg.w + bb.w);
  reinterpret_cast<ushort4*>(out_row)[t] = o;
}

// ---- prep: ln1(x)->hbuf  +  4 weight transpose-converts, one launch ----
__global__ __launch_bounds__(256) void prep_kernel(
    const float* __restrict__ x, const float* __restrict__ ln1g,
    const float* __restrict__ ln1b, u16* __restrict__ hbuf,
    const float* __restrict__ Wqkv, u16* __restrict__ wt_qkv,
    const float* __restrict__ Wproj, u16* __restrict__ wt_proj,
    const float* __restrict__ Wfc, u16* __restrict__ wt_fc,
    const float* __restrict__ Wout, u16* __restrict__ wt_out) {
  __shared__ float smem[32 * 33];
  int id = blockIdx.x;
  const int t = threadIdx.x;
  if (id < 4096) {
    const float4 v = reinterpret_cast<const float4*>(x + (size_t)id * 1024)[t];
    ln_body(v, ln1g, ln1b, hbuf + (size_t)id * 1024, t, smem);
    return;
  }
  id -= 4096;
  const float* W;
  u16* Wt;
  int K, N, nbx;
  if (id < 3072) {
    W = Wqkv; Wt = wt_qkv; K = 1024; N = 3072; nbx = 96;
  } else if (id < 3072 + 1024) {
    id -= 3072; W = Wproj; Wt = wt_proj; K = 1024; N = 1024; nbx = 32;
  } else if (id < 3072 + 1024 + 4096) {
    id -= 3072 + 1024; W = Wfc; Wt = wt_fc; K = 1024; N = 4096; nbx = 128;
  } else {
    id -= 3072 + 1024 + 4096; W = Wout; Wt = wt_out; K = 4096; N = 1024; nbx = 32;
  }
  float(*tile)[33] = (float(*)[33])smem;
  const int c0 = (id % nbx) * 32, r0 = (id / nbx) * 32;
  const int tx = t & 31, ty = t >> 5;  // ty 0..7
#pragma unroll
  for (int j = 0; j < 4; ++j)
    tile[ty + j * 8][tx] = W[(size_t)(r0 + ty + j * 8) * N + c0 + tx];
  __syncthreads();
#pragma unroll
  for (int j = 0; j < 4; ++j) {
    const int n = c0 + ty + j * 8, k = r0 + tx;
    Wt[(size_t)n * K + k] = f2bf(tile[tx][ty + j * 8]);
  }
}

// ------- fused: x2 = x + bproj + P0 + P1 (bf16 partials); hbuf = LN(x2) bf16 -------
__global__ __launch_bounds__(256) void proj_reduce_ln(const float* __restrict__ x,
                                                      const float* __restrict__ bias,
                                                      const u16* __restrict__ P0,
                                                      const u16* __restrict__ P1,
                                                      const float* __restrict__ g,
                                                      const float* __restrict__ be,
                                                      float* __restrict__ x2,
                                                      u16* __restrict__ hbuf) {
  const int row = blockIdx.x, t = threadIdx.x;
  const size_t off = (size_t)row * 1024;
  __shared__ float red[8];
  const float4 xv = reinterpret_cast<const float4*>(x + off)[t];
  const float4 bv = reinterpret_cast<const float4*>(bias)[t];
  const ushort4 p0 = reinterpret_cast<const ushort4*>(P0 + off)[t];
  const ushort4 p1 = reinterpret_cast<const ushort4*>(P1 + off)[t];
  float4 v;
  v.x = xv.x + bv.x + bf2f(p0.x) + bf2f(p1.x);
  v.y = xv.y + bv.y + bf2f(p0.y) + bf2f(p1.y);
  v.z = xv.z + bv.z + bf2f(p0.z) + bf2f(p1.z);
  v.w = xv.w + bv.w + bf2f(p0.w) + bf2f(p1.w);
  reinterpret_cast<float4*>(x2 + off)[t] = v;
  ln_body(v, g, be, hbuf + off, t, red);
}

// ------- fused: d_out = x2 + bout + P0+P1 (bf16 partials, split-K=2) -------
__global__ __launch_bounds__(256) void out_reduce(const float* __restrict__ x2,
                                                  const float* __restrict__ bias,
                                                  const u16* __restrict__ P0,
                                                  const u16* __restrict__ P1,
                                                  float* __restrict__ dout) {
  const int row = blockIdx.x, t = threadIdx.x;
  const size_t off = (size_t)row * 1024;
  const float4 xv = reinterpret_cast<const float4*>(x2 + off)[t];
  const float4 bv = reinterpret_cast<const float4*>(bias)[t];
  const ushort4 a = reinterpret_cast<const ushort4*>(P0 + off)[t];
  const ushort4 b = reinterpret_cast<const ushort4*>(P1 + off)[t];
  f32x4 o;
  o[0] = xv.x + bv.x + bf2f(a.x) + bf2f(b.x);
  o[1] = xv.y + bv.y + bf2f(a.y) + bf2f(b.y);
  o[2] = xv.z + bv.z + bf2f(a.z) + bf2f(b.z);
  o[3] = xv.w + bv.w + bf2f(a.w) + bf2f(b.w);
  // final output, never re-read on device: non-temporal
  __builtin_nontemporal_store(o, reinterpret_cast<f32x4*>(dout + off) + t);
}

// ---------------- GEMM: C[M,N] = A[M,K](bf16) @ Bt[N,K]^T(bf16) + epilogue --------
// BK=64 (32 MFMA per barrier drain).  Logical tiles: (bm = m-tile, bn = n-tile,
// zz = K-slice), derived from a bijective remap of the linear block id:
//   1) XCD chunking: block lands on XCD (lin%8); give each XCD a CONTIGUOUS
//      tile range (requires total%8==0 — true for all launches here).
//   2) 8x8 grouped raster within the chunk: the ~64 blocks concurrently
//      resident per XCD then cover an 8m x 8n tile square -> working set
//      8*256KB(A) + 8*256KB(B) = 4MB = one XCD's L2.
// C-stores are NON-TEMPORAL: outputs are never re-read inside the producing
// kernel, and the 4MB A/B panel working set = exactly one XCD L2 — streaming
// the C-write through L2 was evicting the panels (fc: FETCH 28MB vs 16 ideal).
// F_PART4: bf16 partial at pp[z].  F_VT: blocks with n0>=2048 write C transposed
// into pp0 as V^T [b,h,d,s] (fuses the V-transpose into the qkv epilogue).
enum { F_BIAS = 1, F_RESID = 2, F_RELU = 4, F_BF16 = 8, F_PART4 = 32, F_VT = 64 };

template <int FLAGS>
__global__ __launch_bounds__(256, 2) void gemm_bt(const u16* __restrict__ A,
                                                  const u16* __restrict__ Bt,
                                                  const float* __restrict__ bias,
                                                  const float* __restrict__ resid,
                                                  void* __restrict__ Cout,
                                                  u16* __restrict__ pp0, u16* __restrict__ pp1,
                                                  u16* __restrict__ pp2, u16* __restrict__ pp3,
                                                  int M, int N, int K, int Kst) {
  __shared__ __attribute__((aligned(16))) u16 sA[2][128 * 32];
  __shared__ __attribute__((aligned(16))) u16 sB[2][128 * 32];

  // ---- block-id remap: XCD chunk + 8x8 grouped raster (bijective) ----
  const int gx = gridDim.x, gy = gridDim.y;
  const int tilesPerZ = gx * gy;
  int lin = (blockIdx.z * gy + blockIdx.y) * gx + blockIdx.x;
  const int total = tilesPerZ * gridDim.z;
  if (!(total & 7)) lin = (lin & 7) * (total >> 3) + (lin >> 3);
  const int zz = lin / tilesPerZ;
  const int pid = lin - zz * tilesPerZ;
  const int npg = gx << 3;  // tiles per 8-m-row group band
  const int gid = pid / npg;
  const int rem = pid - gid * npg;
  const int fm = gid << 3;
  const int gsm = (gy - fm < 8) ? (gy - fm) : 8;
  const int bm = fm + rem % gsm;
  const int bn = rem / gsm;

  const int t = threadIdx.x, w = t >> 6, L = t & 63, quad = L >> 4, l15 = L & 15;
  const int wm = w >> 1, wn = w & 1;
  const int m0 = bm * 128, n0 = bn * 128;
  const u16* Ag = A + (size_t)m0 * Kst + (size_t)zz * K;
  const u16* Bg = Bt + (size_t)n0 * Kst + (size_t)zz * K;

  f32x4 acc[4][4] = {};

  for (int k0 = 0; k0 < K; k0 += 64) {
    __syncthreads();
#pragma unroll
    for (int h = 0; h < 2; ++h) {
#pragma unroll
      for (int i = 0; i < 2; ++i) {
        const int cp = i * 256 + t, rr = cp >> 2, cc = (cp & 3) << 3;
        gl_lds16(Ag + (size_t)rr * Kst + k0 + h * 32 + cc, &sA[h][(i * 256 + w * 64) * 8]);
      }
#pragma unroll
      for (int i = 0; i < 2; ++i) {
        const int cp = i * 256 + t, rr = cp >> 2, cc = (cp & 3) << 3;
        gl_lds16(Bg + (size_t)rr * Kst + k0 + h * 32 + cc, &sB[h][(i * 256 + w * 64) * 8]);
      }
    }
    __syncthreads();

#pragma unroll
    for (int h = 0; h < 2; ++h) {
      bf16x8 af[4], bfr[4];
#pragma unroll
      for (int m = 0; m < 4; ++m)
        af[m] = *(const bf16x8*)&sA[h][(wm * 64 + m * 16 + l15) * 32 + quad * 8];
#pragma unroll
      for (int n = 0; n < 4; ++n)
        bfr[n] = *(const bf16x8*)&sB[h][(wn * 64 + n * 16 + l15) * 32 + quad * 8];
#pragma unroll
      for (int m = 0; m < 4; ++m)
#pragma unroll
        for (int n = 0; n < 4; ++n)
          acc[m][n] =
              __builtin_amdgcn_mfma_f32_16x16x32_bf16(af[m], bfr[n], acc[m][n], 0, 0, 0);
    }
  }

  if ((FLAGS & F_VT) && n0 >= 2048) {
    // V block of the qkv GEMM: write C transposed into pp0 = Vt [b,h,d,s] (bf16)
#pragma unroll
    for (int m = 0; m < 4; ++m) {
#pragma unroll
      for (int n = 0; n < 4; ++n) {
        const int col = n0 + wn * 64 + n * 16 + l15;
        const float bv = bias[col];
        const int hh = (col - 2048) >> 6, dd = col & 63;
        const int srow = m0 + wm * 64 + m * 16 + quad * 4;
        const int bb = srow >> 11, ss = srow & 2047;
        u16x4 tmp;
        tmp[0] = f2bf(acc[m][n][0] + bv);
        tmp[1] = f2bf(acc[m][n][1] + bv);
        tmp[2] = f2bf(acc[m][n][2] + bv);
        tmp[3] = f2bf(acc[m][n][3] + bv);
        __builtin_nontemporal_store(
            tmp, (u16x4*)(pp0 + ((size_t)((bb * 16 + hh) * 64 + dd)) * 2048 + ss));
      }
    }
    return;
  }

  u16* pbase = nullptr;
  if (FLAGS & F_PART4)
    pbase = (zz == 0) ? pp0 : (zz == 1) ? pp1 : (zz == 2) ? pp2 : pp3;

#pragma unroll
  for (int m = 0; m < 4; ++m) {
#pragma unroll
    for (int n = 0; n < 4; ++n) {
      const int col = n0 + wn * 64 + n * 16 + l15;
      const float bv = (FLAGS & F_BIAS) ? bias[col] : 0.0f;
#pragma unroll
      for (int rr = 0; rr < 4; ++rr) {
        const int row = m0 + wm * 64 + m * 16 + quad * 4 + rr;
        if (FLAGS & F_PART4) {
          __builtin_nontemporal_store(f2bf(acc[m][n][rr]),
                                      &pbase[(size_t)row * N + col]);
        } else {
          float v = acc[m][n][rr] + bv;
          if (FLAGS & F_RESID) v += resid[(size_t)row * N + col];
          if (FLAGS & F_RELU) v = fmaxf(v, 0.0f);
          if (FLAGS & F_BF16)
            __builtin_nontemporal_store(f2bf(v), (u16*)Cout + (size_t)row * N + col);
          else
            __builtin_nontemporal_store(v, (float*)Cout + (size_t)row * N + col);
        }
      }
    }
  }
}

// ---------------- Flash attention (causal), bf16 MFMA, no-max softmax ----------------
// QBLK=128, 8 waves (512 threads) share each 64x64 K/V tile: each staged 16KB
// tile feeds 2x the MFMA work of the QBLK=64 version -> half the tile-stagings.
// Split-KV (no-max softmax => partials exactly additive): qt>=8 splits into
// chunk0 = kv tiles [0,16) -> acc0, chunk1 = [16, 2qt+2) -> acc1; LPT order.
// Combine is a SEPARATE dispatch: R5 measured that fusing it via device-scope
// fences (__threadfence) costs ~180us in L2 wb/inv serialization on CDNA4's
// non-coherent per-XCD L2s — a kernel boundary IS the cheap device-wide barrier.
// Staging: single-buffered async global_load_lds (R1: LDS dbuf cost occupancy,
// net loss; R7: T14 reg-staging split cost an extra barrier+lgkmcnt, net loss
// — gload_lds direct is the measured optimum here).
// K/V LDS tiles keep the 16B-slot XOR swizzle (conflict-free fragment reads):
// linear global_load_lds dest + inverse-swizzled GLOBAL source + swizzled read.
__global__ __launch_bounds__(512) void flash_attn(const u16* __restrict__ qkv,
                                                  const u16* __restrict__ Vt,
                                                  u16* __restrict__ y,
                                                  float* __restrict__ acc0,
                                                  float* __restrict__ acc1,
                                                  float* __restrict__ lacc0,
                                                  float* __restrict__ lacc1) {
  constexpr int S = 2048, D3 = 3072, D = 1024;
  constexpr float Csc = 0.125f * 1.44269504088896f;  // scale * log2(e)
  __shared__ __attribute__((aligned(16))) u16 sK[64 * 64];        // swizzled [kv][k]
  __shared__ __attribute__((aligned(16))) u16 sV[64 * 64];        // swizzled [d][kv]
  __shared__ __attribute__((aligned(16))) u16 sP[8][2 * 16 * 40]; // per-wave, pad stride 40

  // LPT schedule: e = bid>>5 (0..23), bh = bid&31 spreads heads.
  //   e<8             : qt=8+e,  chunk0 (kv tiles [0,16)), 16 tiles     -> acc0
  //   e>=8, even e-8  : qt=7-j  single (tiles [0,2qt+2)), 16-2j tiles   -> y
  //   e>=8, odd  e-8  : qt=15-j chunk1 (tiles [16,2qt+2)), 16-2j tiles  -> acc1
  const int bid = blockIdx.x;
  const int bh = bid & 31;
  const int e = bid >> 5;
  int qt, it0, it1, part;  // part: 0 = direct y, 1 = acc0, 2 = acc1
  if (e < 8) {
    qt = 8 + e; it0 = 0; it1 = 16; part = 1;
  } else {
    const int j = (e - 8) >> 1;
    if (((e - 8) & 1) == 0) {
      qt = 7 - j; it0 = 0; it1 = 2 * qt + 2; part = 0;
    } else {
      qt = 15 - j; it0 = 16; it1 = 2 * qt + 2; part = 2;
    }
  }
  const int b = bh >> 4, h = bh & 15;
  const int q0 = qt * 128;

  const int t = threadIdx.x, w = t >> 6, L = t & 63, quad = L >> 4, l15 = L & 15;
  const int qw = q0 + w * 16;  // this wave's first q row

  const u16* qbase = qkv + (size_t)(b * S) * D3 + h * 64;
  const u16* Kbase = qbase + D;
  const u16* Vbase = Vt + (size_t)((b * 16 + h) * 64) * S;

  // staging coords (512 threads cover the 512 16B-slots of one 8KB tile):
  // slot p = t; row = p>>3, logical col block ks = (p&7) ^ (row&7)
  const int srow = t >> 3;
  const int k8 = ((t & 7) ^ (srow & 7)) << 3;
  const u16* Ksrc = Kbase + (size_t)srow * D3 + k8;  // + kv0*D3 per tile
  const u16* Vsrc = Vbase + (size_t)srow * S + k8;   // + kv0 per tile
  u16* sKdst = &sK[(w * 64) * 8];  // wave-uniform base; HW adds lane*16
  u16* sVdst = &sV[(w * 64) * 8];

  bf16x8 aQ[2];
#pragma unroll
  for (int kk = 0; kk < 2; ++kk)
    aQ[kk] = *(const bf16x8*)(qbase + (size_t)(qw + l15) * D3 + kk * 32 + quad * 8);

  bf16x8 ones;
#pragma unroll
  for (int i = 0; i < 8; ++i) ones[i] = (__bf16)1.0f;

  f32x4 acc[4] = {};
  f32x4 lacc = {};

  u16* sPw = sP[w];
  const int swz = l15 & 7;  // == row&7 for all fragment rows (row = n*16+l15)

  // prologue: stage first tile
  gl_lds16(Ksrc + (size_t)(it0 * 64) * D3, sKdst);
  gl_lds16(Vsrc + it0 * 64, sVdst);

  for (int it = it0; it < it1; ++it) {
    const int kv0 = it * 64;
    asm volatile("s_waitcnt vmcnt(0)" ::: "memory");
    __builtin_amdgcn_s_barrier();

    f32x4 s[4] = {};
    __builtin_amdgcn_s_setprio(1);
#pragma unroll
    for (int kk = 0; kk < 2; ++kk) {
#pragma unroll
      for (int n = 0; n < 4; ++n) {
        const bf16x8 bK =
            *(const bf16x8*)&sK[(n * 16 + l15) * 64 + ((kk * 4 + quad) ^ swz) * 8];
        s[n] = __builtin_amdgcn_mfma_f32_16x16x32_bf16(aQ[kk], bK, s[n], 0, 0, 0);
      }
    }
    __builtin_amdgcn_s_setprio(0);

    if (kv0 + 63 > qw) {
#pragma unroll
      for (int n = 0; n < 4; ++n) {
        const int col = kv0 + n * 16 + l15;
#pragma unroll
        for (int r = 0; r < 4; ++r) {
          const int row = qw + quad * 4 + r;
          const float p = __builtin_amdgcn_exp2f(s[n][r] * Csc);
          s[n][r] = (col > row) ? 0.0f : p;
        }
      }
    } else {
#pragma unroll
      for (int n = 0; n < 4; ++n)
#pragma unroll
        for (int r = 0; r < 4; ++r) s[n][r] = __builtin_amdgcn_exp2f(s[n][r] * Csc);
    }

#pragma unroll
    for (int n = 0; n < 4; ++n)
#pragma unroll
      for (int r = 0; r < 4; ++r)
        sPw[(n >> 1) * 640 + (quad * 4 + r) * 40 + (n & 1) * 16 + l15] = f2bf(s[n][r]);

    __builtin_amdgcn_s_setprio(1);
#pragma unroll
    for (int kk = 0; kk < 2; ++kk) {
      const bf16x8 aP = *(const bf16x8*)&sPw[kk * 640 + l15 * 40 + quad * 8];
      lacc = __builtin_amdgcn_mfma_f32_16x16x32_bf16(aP, ones, lacc, 0, 0, 0);
#pragma unroll
      for (int dn = 0; dn < 4; ++dn) {
        const bf16x8 bV =
            *(const bf16x8*)&sV[(dn * 16 + l15) * 64 + ((kk * 4 + quad) ^ swz) * 8];
        acc[dn] = __builtin_amdgcn_mfma_f32_16x16x32_bf16(aP, bV, acc[dn], 0, 0, 0);
      }
    }
    __builtin_amdgcn_s_setprio(0);

    // all waves' ds_reads from sK/sV retired before anyone overwrites them
    asm volatile("s_waitcnt lgkmcnt(0)" ::: "memory");
    __builtin_amdgcn_s_barrier();
    if (it + 1 < it1) {
      const int kvn = kv0 + 64;
      gl_lds16(Ksrc + (size_t)kvn * D3, sKdst);
      gl_lds16(Vsrc + kvn, sVdst);
    }
  }

  if (part == 0) {
#pragma unroll
    for (int r = 0; r < 4; ++r) {
      const float inv = 1.0f / lacc[r];
      const int row = qw + quad * 4 + r;
      u16* yb = y + (size_t)(b * S + row) * D + h * 64 + l15;
#pragma unroll
      for (int dn = 0; dn < 4; ++dn) yb[dn * 16] = f2bf(acc[dn][r] * inv);
    }
  } else {
    float* accP = (part == 1) ? acc0 : acc1;
    float* laccP = (part == 1) ? lacc0 : lacc1;
#pragma unroll
    for (int r = 0; r < 4; ++r) {
      const int row = qw + quad * 4 + r;
      const int g = (bh << 10) + (row - 1024);  // rows 1024..2047 only (qt>=8)
      float* ap = accP + (size_t)g * 64 + l15;
#pragma unroll
      for (int dn = 0; dn < 4; ++dn) ap[dn * 16] = acc[dn][r];
      if (l15 == 0) laccP[g] = lacc[r];
    }
  }
}

// ---- combine the two split-KV partials: y = (a0+a1)/(l0+l1), rows 1024..2047 ----
__global__ __launch_bounds__(256) void attn_combine(const float* __restrict__ acc0,
                                                    const float* __restrict__ acc1,
                                                    const float* __restrict__ lacc0,
                                                    const float* __restrict__ lacc1,
                                                    u16* __restrict__ y) {
  const int t = threadIdx.x;
  const int g = blockIdx.x * 4 + (t >> 6);  // 0..32767 (bh*1024 + ri)
  const int d = t & 63;
  const int bh = g >> 10, ri = g & 1023;
  const int b = bh >> 4, h = bh & 15;
  const int row = 1024 + ri;
  const size_t po = (size_t)g * 64 + d;
  const float l = lacc0[g] + lacc1[g];
  const float v = (acc0[po] + acc1[po]) / l;
  y[((size_t)(b * 2048 + row)) * 1024 + h * 64 + d] = f2bf(v);
}

// ---------------- host ----------------
extern "C" void kernel_launch(void* const* d_in, const int* in_sizes, int n_in,
                              void* d_out, int out_size, void* d_ws, size_t ws_size,
                              hipStream_t stream) {
  const float* x = (const float*)d_in[0];
  const float* ln1g = (const float*)d_in[1];
  const float* ln1b = (const float*)d_in[2];
  const float* ln2g = (const float*)d_in[3];
  const float* ln2b = (const float*)d_in[4];
  const float* Wqkv = (const float*)d_in[5];
  const float* bqkv = (const float*)d_in[6];
  const float* Wproj = (const float*)d_in[7];
  const float* bproj = (const float*)d_in[8];
  const float* Wfc = (const float*)d_in[9];
  const float* bfc = (const float*)d_in[10];
  const float* Wout = (const float*)d_in[11];
  const float* bout = (const float*)d_in[12];

  char* ws = (char*)d_ws;
  const size_t MB = 1u << 20;
  // Liveness-based layout; peak 88 MB.
  u16* wt_out = (u16*)(ws + 0 * MB);    //  0- 8  [until out gemm]
  u16* hbuf = (u16*)(ws + 8 * MB);      //  8-16  [ln1->qkv; ln2->fc]
  float* x2 = (float*)(ws + 16 * MB);   // 16-32  [proj_reduce -> out_reduce]
  u16* ybuf = (u16*)(ws + 32 * MB);     // 32-40  [flash -> proj gemm]
  u16* qkvb = (u16*)(ws + 40 * MB);     // 40-64  [qkv gemm -> flash] (Q,K only)
  u16* vtb = (u16*)(ws + 64 * MB);      // 64-72  [qkv gemm (V^T) -> flash]
  u16* wt_qkv = (u16*)(ws + 72 * MB);   // 72-78  [until qkv gemm]
  u16* wt_proj = (u16*)(ws + 78 * MB);  // 78-80  [until proj gemm]
  u16* wt_fc = (u16*)(ws + 80 * MB);    // 80-88  [until fc gemm]
  u16* projP0 = (u16*)(ws + 40 * MB);   // 40-48  bf16 proj partials (qkvb dead)
  u16* projP1 = (u16*)(ws + 48 * MB);   // 48-56
  u16* m1 = (u16*)(ws + 40 * MB);       // 40-72  fc out bf16 (projP dead)
  u16* po0 = (u16*)(ws + 8 * MB);       // hbuf dead after fc (split-K=2 partials)
  u16* po1 = (u16*)(ws + 32 * MB);      // ybuf dead after proj
  // split-KV partials, live only flash -> combine (hbuf/x2 contents dead then):
  float* facc0 = (float*)(ws + 8 * MB);   //  8-16  (hbuf region, dead during flash)
  float* facc1 = (float*)(ws + 16 * MB);  // 16-24  (x2 region, written later)
  float* flacc0 = (float*)(ws + 24 * MB); // 24-24.125
  float* flacc1 = (float*)(ws + 25 * MB); // 25-25.125

  // ln1 + all 4 weight transposes in one launch
  prep_kernel<<<4096 + 3072 + 1024 + 4096 + 4096, 256, 0, stream>>>(
      x, ln1g, ln1b, hbuf, Wqkv, wt_qkv, Wproj, wt_proj, Wfc, wt_fc, Wout, wt_out);

  // qkv GEMM; V-columns (n0>=2048) written transposed straight into vtb
  gemm_bt<F_BIAS | F_BF16 | F_VT><<<dim3(24, 32), 256, 0, stream>>>(
      hbuf, wt_qkv, bqkv, nullptr, qkvb, vtb, nullptr, nullptr, nullptr,
      4096, 3072, 1024, 1024);
  flash_attn<<<768, 512, 0, stream>>>(qkvb, vtb, ybuf, facc0, facc1, flacc0, flacc1);
  attn_combine<<<8192, 256, 0, stream>>>(facc0, facc1, flacc0, flacc1, ybuf);

  // proj: split-K=2 into bf16 partials, then fused residual+bias+LN2
  gemm_bt<F_PART4><<<dim3(8, 32, 2), 256, 0, stream>>>(
      ybuf, wt_proj, nullptr, nullptr, nullptr, projP0, projP1, nullptr, nullptr,
      4096, 1024, 512, 1024);
  proj_reduce_ln<<<4096, 256, 0, stream>>>(x, bproj, projP0, projP1, ln2g, ln2b, x2, hbuf);

  gemm_bt<F_BIAS | F_RELU | F_BF16><<<dim3(32, 32), 256, 0, stream>>>(
      hbuf, wt_fc, bfc, nullptr, m1, nullptr, nullptr, nullptr, nullptr,
      4096, 4096, 1024, 1024);

  // out: split-K=2 into bf16 partials, then fused residual+bias reduce
  gemm_bt<F_PART4><<<dim3(8, 32, 2), 256, 0, stream>>>(
      m1, wt_out, nullptr, nullptr, nullptr, po0, po1, nullptr, nullptr,
      4096, 1024, 2048, 4096);
  out_reduce<<<4096, 256, 0, stream>>>(x2, bout, po0, po1, (float*)d_out);
}

// Round 9
// 321.035 us; speedup vs baseline: 1.0927x; 1.0927x over previous
//
#include <hip/hip_runtime.h>

typedef unsigned short u16;
typedef __attribute__((ext_vector_type(8))) __bf16 bf16x8;
typedef __attribute__((ext_vector_type(4))) float f32x4;

#define DEV __device__ __forceinline__

DEV u16 f2bf(float f) {  // RTNE float->bf16
  unsigned u = __float_as_uint(f);
  u += 0x7fffu + ((u >> 16) & 1u);
  return (u16)(u >> 16);
}
DEV float bf2f(u16 u) { return __uint_as_float((unsigned)u << 16); }

// async global->LDS, 16B per lane. LDS dest is wave-uniform base + lane*16.
DEV void gl_lds16(const void* g, void* l) {
  __builtin_amdgcn_global_load_lds(
      (const __attribute__((address_space(1))) void*)(uintptr_t)g,
      (__attribute__((address_space(3))) void*)(unsigned)(uintptr_t)l, 16, 0, 0);
}

DEV float wave_sum64(float v) {
#pragma unroll
  for (int off = 32; off > 0; off >>= 1) v += __shfl_down(v, off);
  return v;  // lane 0 holds sum
}

// ---------------- LN body (shared by prep & proj_reduce_ln) ----------------
DEV void ln_body(const float4 v, const float* g, const float* be, u16* out_row, int t,
                 float* red) {
  const int w = t >> 6, L = t & 63;
  float s = v.x + v.y + v.z + v.w;
  s = wave_sum64(s);
  if (L == 0) red[w] = s;
  __syncthreads();
  const float mean = (red[0] + red[1] + red[2] + red[3]) * (1.0f / 1024.0f);
  const float dx = v.x - mean, dy = v.y - mean, dz = v.z - mean, dw = v.w - mean;
  float q = dx * dx + dy * dy + dz * dz + dw * dw;
  q = wave_sum64(q);
  if (L == 0) red[4 + w] = q;
  __syncthreads();
  const float var = (red[4] + red[5] + red[6] + red[7]) * (1.0f / 1024.0f);
  const float rs = rsqrtf(var + 1e-5f);
  const float4 gg = reinterpret_cast<const float4*>(g)[t];
  const float4 bb = reinterpret_cast<const float4*>(be)[t];
  ushort4 o;
  o.x = f2bf(dx * rs * gg.x + bb.x);
  o.y = f2bf(dy * rs * gg.y + bb.y);
  o.z = f2bf(dz * rs * gg.z + bb.z);
  o.w = f2bf(dw * rs * gg.w + bb.w);
  reinterpret_cast<ushort4*>(out_row)[t] = o;
}

// ---- prep: ln1(x)->hbuf  +  4 weight transpose-converts, one launch ----
__global__ __launch_bounds__(256) void prep_kernel(
    const float* __restrict__ x, const float* __restrict__ ln1g,
    const float* __restrict__ ln1b, u16* __restrict__ hbuf,
    const float* __restrict__ Wqkv, u16* __restrict__ wt_qkv,
    const float* __restrict__ Wproj, u16* __restrict__ wt_proj,
    const float* __restrict__ Wfc, u16* __restrict__ wt_fc,
    const float* __restrict__ Wout, u16* __restrict__ wt_out) {
  __shared__ float smem[32 * 33];
  int id = blockIdx.x;
  const int t = threadIdx.x;
  if (id < 4096) {
    const float4 v = reinterpret_cast<const float4*>(x + (size_t)id * 1024)[t];
    ln_body(v, ln1g, ln1b, hbuf + (size_t)id * 1024, t, smem);
    return;
  }
  id -= 4096;
  const float* W;
  u16* Wt;
  int K, N, nbx;
  if (id < 3072) {
    W = Wqkv; Wt = wt_qkv; K = 1024; N = 3072; nbx = 96;
  } else if (id < 3072 + 1024) {
    id -= 3072; W = Wproj; Wt = wt_proj; K = 1024; N = 1024; nbx = 32;
  } else if (id < 3072 + 1024 + 4096) {
    id -= 3072 + 1024; W = Wfc; Wt = wt_fc; K = 1024; N = 4096; nbx = 128;
  } else {
    id -= 3072 + 1024 + 4096; W = Wout; Wt = wt_out; K = 4096; N = 1024; nbx = 32;
  }
  float(*tile)[33] = (float(*)[33])smem;
  const int c0 = (id % nbx) * 32, r0 = (id / nbx) * 32;
  const int tx = t & 31, ty = t >> 5;  // ty 0..7
#pragma unroll
  for (int j = 0; j < 4; ++j)
    tile[ty + j * 8][tx] = W[(size_t)(r0 + ty + j * 8) * N + c0 + tx];
  __syncthreads();
#pragma unroll
  for (int j = 0; j < 4; ++j) {
    const int n = c0 + ty + j * 8, k = r0 + tx;
    Wt[(size_t)n * K + k] = f2bf(tile[tx][ty + j * 8]);
  }
}

// ------- fused: x2 = x + bproj + P0 + P1 (bf16 partials); hbuf = LN(x2) bf16 -------
__global__ __launch_bounds__(256) void proj_reduce_ln(const float* __restrict__ x,
                                                      const float* __restrict__ bias,
                                                      const u16* __restrict__ P0,
                                                      const u16* __restrict__ P1,
                                                      const float* __restrict__ g,
                                                      const float* __restrict__ be,
                                                      float* __restrict__ x2,
                                                      u16* __restrict__ hbuf) {
  const int row = blockIdx.x, t = threadIdx.x;
  const size_t off = (size_t)row * 1024;
  __shared__ float red[8];
  const float4 xv = reinterpret_cast<const float4*>(x + off)[t];
  const float4 bv = reinterpret_cast<const float4*>(bias)[t];
  const ushort4 p0 = reinterpret_cast<const ushort4*>(P0 + off)[t];
  const ushort4 p1 = reinterpret_cast<const ushort4*>(P1 + off)[t];
  float4 v;
  v.x = xv.x + bv.x + bf2f(p0.x) + bf2f(p1.x);
  v.y = xv.y + bv.y + bf2f(p0.y) + bf2f(p1.y);
  v.z = xv.z + bv.z + bf2f(p0.z) + bf2f(p1.z);
  v.w = xv.w + bv.w + bf2f(p0.w) + bf2f(p1.w);
  reinterpret_cast<float4*>(x2 + off)[t] = v;
  ln_body(v, g, be, hbuf + off, t, red);
}

// ------- fused: d_out = x2 + bout + P0+P1 (bf16 partials, split-K=2) -------
__global__ __launch_bounds__(256) void out_reduce(const float* __restrict__ x2,
                                                  const float* __restrict__ bias,
                                                  const u16* __restrict__ P0,
                                                  const u16* __restrict__ P1,
                                                  float* __restrict__ dout) {
  const int row = blockIdx.x, t = threadIdx.x;
  const size_t off = (size_t)row * 1024;
  const float4 xv = reinterpret_cast<const float4*>(x2 + off)[t];
  const float4 bv = reinterpret_cast<const float4*>(bias)[t];
  const ushort4 a = reinterpret_cast<const ushort4*>(P0 + off)[t];
  const ushort4 b = reinterpret_cast<const ushort4*>(P1 + off)[t];
  float4 o;
  o.x = xv.x + bv.x + bf2f(a.x) + bf2f(b.x);
  o.y = xv.y + bv.y + bf2f(a.y) + bf2f(b.y);
  o.z = xv.z + bv.z + bf2f(a.z) + bf2f(b.z);
  o.w = xv.w + bv.w + bf2f(a.w) + bf2f(b.w);
  reinterpret_cast<float4*>(dout + off)[t] = o;
}

// ---------------- GEMM: C[M,N] = A[M,K](bf16) @ Bt[N,K]^T(bf16) + epilogue --------
// BK=64 (32 MFMA per barrier drain).  Logical tiles: (bm = m-tile, bn = n-tile,
// zz = K-slice), derived from a bijective remap of the linear block id:
//   1) XCD chunking: block lands on XCD (lin%8); give each XCD a CONTIGUOUS
//      tile range (requires total%8==0 — true for all launches here).
//   2) 8x8 grouped raster within the chunk: the ~64 blocks concurrently
//      resident per XCD then cover an 8m x 8n tile square -> working set
//      8*256KB(A) + 8*256KB(B) = 4MB = one XCD's L2.
// NOTE (R8): non-temporal epilogue stores REGRESSED (scalar strided u16 stores
// rely on L2 write-merge; nt bypassed it -> 1.8x HBM write amplification).
// F_PART4: bf16 partial at pp[z].  F_VT: blocks with n0>=2048 write C transposed
// into pp0 as V^T [b,h,d,s] (fuses the V-transpose into the qkv epilogue).
enum { F_BIAS = 1, F_RESID = 2, F_RELU = 4, F_BF16 = 8, F_PART4 = 32, F_VT = 64 };

template <int FLAGS>
__global__ __launch_bounds__(256, 2) void gemm_bt(const u16* __restrict__ A,
                                                  const u16* __restrict__ Bt,
                                                  const float* __restrict__ bias,
                                                  const float* __restrict__ resid,
                                                  void* __restrict__ Cout,
                                                  u16* __restrict__ pp0, u16* __restrict__ pp1,
                                                  u16* __restrict__ pp2, u16* __restrict__ pp3,
                                                  int M, int N, int K, int Kst) {
  __shared__ __attribute__((aligned(16))) u16 sA[2][128 * 32];
  __shared__ __attribute__((aligned(16))) u16 sB[2][128 * 32];

  // ---- block-id remap: XCD chunk + 8x8 grouped raster (bijective) ----
  const int gx = gridDim.x, gy = gridDim.y;
  const int tilesPerZ = gx * gy;
  int lin = (blockIdx.z * gy + blockIdx.y) * gx + blockIdx.x;
  const int total = tilesPerZ * gridDim.z;
  if (!(total & 7)) lin = (lin & 7) * (total >> 3) + (lin >> 3);
  const int zz = lin / tilesPerZ;
  const int pid = lin - zz * tilesPerZ;
  const int npg = gx << 3;  // tiles per 8-m-row group band
  const int gid = pid / npg;
  const int rem = pid - gid * npg;
  const int fm = gid << 3;
  const int gsm = (gy - fm < 8) ? (gy - fm) : 8;
  const int bm = fm + rem % gsm;
  const int bn = rem / gsm;

  const int t = threadIdx.x, w = t >> 6, L = t & 63, quad = L >> 4, l15 = L & 15;
  const int wm = w >> 1, wn = w & 1;
  const int m0 = bm * 128, n0 = bn * 128;
  const u16* Ag = A + (size_t)m0 * Kst + (size_t)zz * K;
  const u16* Bg = Bt + (size_t)n0 * Kst + (size_t)zz * K;

  f32x4 acc[4][4] = {};

  for (int k0 = 0; k0 < K; k0 += 64) {
    __syncthreads();
#pragma unroll
    for (int h = 0; h < 2; ++h) {
#pragma unroll
      for (int i = 0; i < 2; ++i) {
        const int cp = i * 256 + t, rr = cp >> 2, cc = (cp & 3) << 3;
        gl_lds16(Ag + (size_t)rr * Kst + k0 + h * 32 + cc, &sA[h][(i * 256 + w * 64) * 8]);
      }
#pragma unroll
      for (int i = 0; i < 2; ++i) {
        const int cp = i * 256 + t, rr = cp >> 2, cc = (cp & 3) << 3;
        gl_lds16(Bg + (size_t)rr * Kst + k0 + h * 32 + cc, &sB[h][(i * 256 + w * 64) * 8]);
      }
    }
    __syncthreads();

#pragma unroll
    for (int h = 0; h < 2; ++h) {
      bf16x8 af[4], bfr[4];
#pragma unroll
      for (int m = 0; m < 4; ++m)
        af[m] = *(const bf16x8*)&sA[h][(wm * 64 + m * 16 + l15) * 32 + quad * 8];
#pragma unroll
      for (int n = 0; n < 4; ++n)
        bfr[n] = *(const bf16x8*)&sB[h][(wn * 64 + n * 16 + l15) * 32 + quad * 8];
#pragma unroll
      for (int m = 0; m < 4; ++m)
#pragma unroll
        for (int n = 0; n < 4; ++n)
          acc[m][n] =
              __builtin_amdgcn_mfma_f32_16x16x32_bf16(af[m], bfr[n], acc[m][n], 0, 0, 0);
    }
  }

  if ((FLAGS & F_VT) && n0 >= 2048) {
    // V block of the qkv GEMM: write C transposed into pp0 = Vt [b,h,d,s] (bf16)
#pragma unroll
    for (int m = 0; m < 4; ++m) {
#pragma unroll
      for (int n = 0; n < 4; ++n) {
        const int col = n0 + wn * 64 + n * 16 + l15;
        const float bv = bias[col];
        const int hh = (col - 2048) >> 6, dd = col & 63;
        const int srow = m0 + wm * 64 + m * 16 + quad * 4;
        const int bb = srow >> 11, ss = srow & 2047;
        ushort4 tmp;
        tmp.x = f2bf(acc[m][n][0] + bv);
        tmp.y = f2bf(acc[m][n][1] + bv);
        tmp.z = f2bf(acc[m][n][2] + bv);
        tmp.w = f2bf(acc[m][n][3] + bv);
        *(ushort4*)(pp0 + ((size_t)((bb * 16 + hh) * 64 + dd)) * 2048 + ss) = tmp;
      }
    }
    return;
  }

  u16* pbase = nullptr;
  if (FLAGS & F_PART4)
    pbase = (zz == 0) ? pp0 : (zz == 1) ? pp1 : (zz == 2) ? pp2 : pp3;

#pragma unroll
  for (int m = 0; m < 4; ++m) {
#pragma unroll
    for (int n = 0; n < 4; ++n) {
      const int col = n0 + wn * 64 + n * 16 + l15;
      const float bv = (FLAGS & F_BIAS) ? bias[col] : 0.0f;
#pragma unroll
      for (int rr = 0; rr < 4; ++rr) {
        const int row = m0 + wm * 64 + m * 16 + quad * 4 + rr;
        if (FLAGS & F_PART4) {
          pbase[(size_t)row * N + col] = f2bf(acc[m][n][rr]);
        } else {
          float v = acc[m][n][rr] + bv;
          if (FLAGS & F_RESID) v += resid[(size_t)row * N + col];
          if (FLAGS & F_RELU) v = fmaxf(v, 0.0f);
          if (FLAGS & F_BF16)
            ((u16*)Cout)[(size_t)row * N + col] = f2bf(v);
          else
            ((float*)Cout)[(size_t)row * N + col] = v;
        }
      }
    }
  }
}

// ---------------- Flash attention (causal), bf16 MFMA, no-max softmax ----------------
// QBLK=128, 8 waves (512 threads) share each 64x64 K/V tile: each staged 16KB
// tile feeds 2x the MFMA work of the QBLK=64 version -> half the tile-stagings.
// Split-KV (no-max softmax => partials exactly additive): qt>=8 splits into
// chunk0 = kv tiles [0,16) -> acc0, chunk1 = [16, 2qt+2) -> acc1; LPT order.
// Combine is a SEPARATE dispatch: R5 measured that fusing it via device-scope
// fences (__threadfence) costs ~180us in L2 wb/inv serialization on CDNA4's
// non-coherent per-XCD L2s — a kernel boundary IS the cheap device-wide barrier.
// Staging: single-buffered async global_load_lds (R1: LDS dbuf cost occupancy,
// net loss; R7: T14 reg-staging split cost an extra barrier+lgkmcnt, net loss
// — gload_lds direct is the measured optimum here).
// K/V LDS tiles keep the 16B-slot XOR swizzle (conflict-free fragment reads):
// linear global_load_lds dest + inverse-swizzled GLOBAL source + swizzled read.
__global__ __launch_bounds__(512) void flash_attn(const u16* __restrict__ qkv,
                                                  const u16* __restrict__ Vt,
                                                  u16* __restrict__ y,
                                                  float* __restrict__ acc0,
                                                  float* __restrict__ acc1,
                                                  float* __restrict__ lacc0,
                                                  float* __restrict__ lacc1) {
  constexpr int S = 2048, D3 = 3072, D = 1024;
  constexpr float Csc = 0.125f * 1.44269504088896f;  // scale * log2(e)
  __shared__ __attribute__((aligned(16))) u16 sK[64 * 64];        // swizzled [kv][k]
  __shared__ __attribute__((aligned(16))) u16 sV[64 * 64];        // swizzled [d][kv]
  __shared__ __attribute__((aligned(16))) u16 sP[8][2 * 16 * 40]; // per-wave, pad stride 40

  // LPT schedule: e = bid>>5 (0..23), bh = bid&31 spreads heads.
  //   e<8             : qt=8+e,  chunk0 (kv tiles [0,16)), 16 tiles     -> acc0
  //   e>=8, even e-8  : qt=7-j  single (tiles [0,2qt+2)), 16-2j tiles   -> y
  //   e>=8, odd  e-8  : qt=15-j chunk1 (tiles [16,2qt+2)), 16-2j tiles  -> acc1
  const int bid = blockIdx.x;
  const int bh = bid & 31;
  const int e = bid >> 5;
  int qt, it0, it1, part;  // part: 0 = direct y, 1 = acc0, 2 = acc1
  if (e < 8) {
    qt = 8 + e; it0 = 0; it1 = 16; part = 1;
  } else {
    const int j = (e - 8) >> 1;
    if (((e - 8) & 1) == 0) {
      qt = 7 - j; it0 = 0; it1 = 2 * qt + 2; part = 0;
    } else {
      qt = 15 - j; it0 = 16; it1 = 2 * qt + 2; part = 2;
    }
  }
  const int b = bh >> 4, h = bh & 15;
  const int q0 = qt * 128;

  const int t = threadIdx.x, w = t >> 6, L = t & 63, quad = L >> 4, l15 = L & 15;
  const int qw = q0 + w * 16;  // this wave's first q row

  const u16* qbase = qkv + (size_t)(b * S) * D3 + h * 64;
  const u16* Kbase = qbase + D;
  const u16* Vbase = Vt + (size_t)((b * 16 + h) * 64) * S;

  // staging coords (512 threads cover the 512 16B-slots of one 8KB tile):
  // slot p = t; row = p>>3, logical col block ks = (p&7) ^ (row&7)
  const int srow = t >> 3;
  const int k8 = ((t & 7) ^ (srow & 7)) << 3;
  const u16* Ksrc = Kbase + (size_t)srow * D3 + k8;  // + kv0*D3 per tile
  const u16* Vsrc = Vbase + (size_t)srow * S + k8;   // + kv0 per tile
  u16* sKdst = &sK[(w * 64) * 8];  // wave-uniform base; HW adds lane*16
  u16* sVdst = &sV[(w * 64) * 8];

  bf16x8 aQ[2];
#pragma unroll
  for (int kk = 0; kk < 2; ++kk)
    aQ[kk] = *(const bf16x8*)(qbase + (size_t)(qw + l15) * D3 + kk * 32 + quad * 8);

  bf16x8 ones;
#pragma unroll
  for (int i = 0; i < 8; ++i) ones[i] = (__bf16)1.0f;

  f32x4 acc[4] = {};
  f32x4 lacc = {};

  u16* sPw = sP[w];
  const int swz = l15 & 7;  // == row&7 for all fragment rows (row = n*16+l15)

  // prologue: stage first tile
  gl_lds16(Ksrc + (size_t)(it0 * 64) * D3, sKdst);
  gl_lds16(Vsrc + it0 * 64, sVdst);

  for (int it = it0; it < it1; ++it) {
    const int kv0 = it * 64;
    asm volatile("s_waitcnt vmcnt(0)" ::: "memory");
    __builtin_amdgcn_s_barrier();

    f32x4 s[4] = {};
    __builtin_amdgcn_s_setprio(1);
#pragma unroll
    for (int kk = 0; kk < 2; ++kk) {
#pragma unroll
      for (int n = 0; n < 4; ++n) {
        const bf16x8 bK =
            *(const bf16x8*)&sK[(n * 16 + l15) * 64 + ((kk * 4 + quad) ^ swz) * 8];
        s[n] = __builtin_amdgcn_mfma_f32_16x16x32_bf16(aQ[kk], bK, s[n], 0, 0, 0);
      }
    }
    __builtin_amdgcn_s_setprio(0);

    if (kv0 + 63 > qw) {
#pragma unroll
      for (int n = 0; n < 4; ++n) {
        const int col = kv0 + n * 16 + l15;
#pragma unroll
        for (int r = 0; r < 4; ++r) {
          const int row = qw + quad * 4 + r;
          const float p = __builtin_amdgcn_exp2f(s[n][r] * Csc);
          s[n][r] = (col > row) ? 0.0f : p;
        }
      }
    } else {
#pragma unroll
      for (int n = 0; n < 4; ++n)
#pragma unroll
        for (int r = 0; r < 4; ++r) s[n][r] = __builtin_amdgcn_exp2f(s[n][r] * Csc);
    }

#pragma unroll
    for (int n = 0; n < 4; ++n)
#pragma unroll
      for (int r = 0; r < 4; ++r)
        sPw[(n >> 1) * 640 + (quad * 4 + r) * 40 + (n & 1) * 16 + l15] = f2bf(s[n][r]);

    __builtin_amdgcn_s_setprio(1);
#pragma unroll
    for (int kk = 0; kk < 2; ++kk) {
      const bf16x8 aP = *(const bf16x8*)&sPw[kk * 640 + l15 * 40 + quad * 8];
      lacc = __builtin_amdgcn_mfma_f32_16x16x32_bf16(aP, ones, lacc, 0, 0, 0);
#pragma unroll
      for (int dn = 0; dn < 4; ++dn) {
        const bf16x8 bV =
            *(const bf16x8*)&sV[(dn * 16 + l15) * 64 + ((kk * 4 + quad) ^ swz) * 8];
        acc[dn] = __builtin_amdgcn_mfma_f32_16x16x32_bf16(aP, bV, acc[dn], 0, 0, 0);
      }
    }
    __builtin_amdgcn_s_setprio(0);

    // all waves' ds_reads from sK/sV retired before anyone overwrites them
    asm volatile("s_waitcnt lgkmcnt(0)" ::: "memory");
    __builtin_amdgcn_s_barrier();
    if (it + 1 < it1) {
      const int kvn = kv0 + 64;
      gl_lds16(Ksrc + (size_t)kvn * D3, sKdst);
      gl_lds16(Vsrc + kvn, sVdst);
    }
  }

  if (part == 0) {
#pragma unroll
    for (int r = 0; r < 4; ++r) {
      const float inv = 1.0f / lacc[r];
      const int row = qw + quad * 4 + r;
      u16* yb = y + (size_t)(b * S + row) * D + h * 64 + l15;
#pragma unroll
      for (int dn = 0; dn < 4; ++dn) yb[dn * 16] = f2bf(acc[dn][r] * inv);
    }
  } else {
    float* accP = (part == 1) ? acc0 : acc1;
    float* laccP = (part == 1) ? lacc0 : lacc1;
#pragma unroll
    for (int r = 0; r < 4; ++r) {
      const int row = qw + quad * 4 + r;
      const int g = (bh << 10) + (row - 1024);  // rows 1024..2047 only (qt>=8)
      float* ap = accP + (size_t)g * 64 + l15;
#pragma unroll
      for (int dn = 0; dn < 4; ++dn) ap[dn * 16] = acc[dn][r];
      if (l15 == 0) laccP[g] = lacc[r];
    }
  }
}

// ---- combine the two split-KV partials: y = (a0+a1)/(l0+l1), rows 1024..2047 ----
__global__ __launch_bounds__(256) void attn_combine(const float* __restrict__ acc0,
                                                    const float* __restrict__ acc1,
                                                    const float* __restrict__ lacc0,
                                                    const float* __restrict__ lacc1,
                                                    u16* __restrict__ y) {
  const int t = threadIdx.x;
  const int g = blockIdx.x * 4 + (t >> 6);  // 0..32767 (bh*1024 + ri)
  const int d = t & 63;
  const int bh = g >> 10, ri = g & 1023;
  const int b = bh >> 4, h = bh & 15;
  const int row = 1024 + ri;
  const size_t po = (size_t)g * 64 + d;
  const float l = lacc0[g] + lacc1[g];
  const float v = (acc0[po] + acc1[po]) / l;
  y[((size_t)(b * 2048 + row)) * 1024 + h * 64 + d] = f2bf(v);
}

// ---------------- host ----------------
extern "C" void kernel_launch(void* const* d_in, const int* in_sizes, int n_in,
                              void* d_out, int out_size, void* d_ws, size_t ws_size,
                              hipStream_t stream) {
  const float* x = (const float*)d_in[0];
  const float* ln1g = (const float*)d_in[1];
  const float* ln1b = (const float*)d_in[2];
  const float* ln2g = (const float*)d_in[3];
  const float* ln2b = (const float*)d_in[4];
  const float* Wqkv = (const float*)d_in[5];
  const float* bqkv = (const float*)d_in[6];
  const float* Wproj = (const float*)d_in[7];
  const float* bproj = (const float*)d_in[8];
  const float* Wfc = (const float*)d_in[9];
  const float* bfc = (const float*)d_in[10];
  const float* Wout = (const float*)d_in[11];
  const float* bout = (const float*)d_in[12];

  char* ws = (char*)d_ws;
  const size_t MB = 1u << 20;
  // Liveness-based layout; peak 88 MB.
  u16* wt_out = (u16*)(ws + 0 * MB);    //  0- 8  [until out gemm]
  u16* hbuf = (u16*)(ws + 8 * MB);      //  8-16  [ln1->qkv; ln2->fc]
  float* x2 = (float*)(ws + 16 * MB);   // 16-32  [proj_reduce -> out_reduce]
  u16* ybuf = (u16*)(ws + 32 * MB);     // 32-40  [flash -> proj gemm]
  u16* qkvb = (u16*)(ws + 40 * MB);     // 40-64  [qkv gemm -> flash] (Q,K only)
  u16* vtb = (u16*)(ws + 64 * MB);      // 64-72  [qkv gemm (V^T) -> flash]
  u16* wt_qkv = (u16*)(ws + 72 * MB);   // 72-78  [until qkv gemm]
  u16* wt_proj = (u16*)(ws + 78 * MB);  // 78-80  [until proj gemm]
  u16* wt_fc = (u16*)(ws + 80 * MB);    // 80-88  [until fc gemm]
  u16* projP0 = (u16*)(ws + 40 * MB);   // 40-48  bf16 proj partials (qkvb dead)
  u16* projP1 = (u16*)(ws + 48 * MB);   // 48-56
  u16* m1 = (u16*)(ws + 40 * MB);       // 40-72  fc out bf16 (projP dead)
  u16* po0 = (u16*)(ws + 8 * MB);       // hbuf dead after fc (split-K=2 partials)
  u16* po1 = (u16*)(ws + 32 * MB);      // ybuf dead after proj
  // split-KV partials, live only flash -> combine (hbuf/x2 contents dead then):
  float* facc0 = (float*)(ws + 8 * MB);   //  8-16  (hbuf region, dead during flash)
  float* facc1 = (float*)(ws + 16 * MB);  // 16-24  (x2 region, written later)
  float* flacc0 = (float*)(ws + 24 * MB); // 24-24.125
  float* flacc1 = (float*)(ws + 25 * MB); // 25-25.125

  // ln1 + all 4 weight transposes in one launch
  prep_kernel<<<4096 + 3072 + 1024 + 4096 + 4096, 256, 0, stream>>>(
      x, ln1g, ln1b, hbuf, Wqkv, wt_qkv, Wproj, wt_proj, Wfc, wt_fc, Wout, wt_out);

  // qkv GEMM; V-columns (n0>=2048) written transposed straight into vtb
  gemm_bt<F_BIAS | F_BF16 | F_VT><<<dim3(24, 32), 256, 0, stream>>>(
      hbuf, wt_qkv, bqkv, nullptr, qkvb, vtb, nullptr, nullptr, nullptr,
      4096, 3072, 1024, 1024);
  flash_attn<<<768, 512, 0, stream>>>(qkvb, vtb, ybuf, facc0, facc1, flacc0, flacc1);
  attn_combine<<<8192, 256, 0, stream>>>(facc0, facc1, flacc0, flacc1, ybuf);

  // proj: split-K=2 into bf16 partials, then fused residual+bias+LN2
  gemm_bt<F_PART4><<<dim3(8, 32, 2), 256, 0, stream>>>(
      ybuf, wt_proj, nullptr, nullptr, nullptr, projP0, projP1, nullptr, nullptr,
      4096, 1024, 512, 1024);
  proj_reduce_ln<<<4096, 256, 0, stream>>>(x, bproj, projP0, projP1, ln2g, ln2b, x2, hbuf);

  gemm_bt<F_BIAS | F_RELU | F_BF16><<<dim3(32, 32), 256, 0, stream>>>(
      hbuf, wt_fc, bfc, nullptr, m1, nullptr, nullptr, nullptr, nullptr,
      4096, 4096, 1024, 1024);

  // out: split-K=2 into bf16 partials, then fused residual+bias reduce
  gemm_bt<F_PART4><<<dim3(8, 32, 2), 256, 0, stream>>>(
      m1, wt_out, nullptr, nullptr, nullptr, po0, po1, nullptr, nullptr,
      4096, 1024, 2048, 4096);
  out_reduce<<<4096, 256, 0, stream>>>(x2, bout, po0, po1, (float*)d_out);
}

// Round 10
// 313.642 us; speedup vs baseline: 1.1185x; 1.0236x over previous
//
#include <hip/hip_runtime.h>

typedef unsigned short u16;
typedef __attribute__((ext_vector_type(8))) __bf16 bf16x8;
typedef __attribute__((ext_vector_type(4))) float f32x4;

#define DEV __device__ __forceinline__

DEV u16 f2bf(float f) {  // RTNE float->bf16
  unsigned u = __float_as_uint(f);
  u += 0x7fffu + ((u >> 16) & 1u);
  return (u16)(u >> 16);
}
DEV float bf2f(u16 u) { return __uint_as_float((unsigned)u << 16); }

// async global->LDS, 16B per lane. LDS dest is wave-uniform base + lane*16.
DEV void gl_lds16(const void* g, void* l) {
  __builtin_amdgcn_global_load_lds(
      (const __attribute__((address_space(1))) void*)(uintptr_t)g,
      (__attribute__((address_space(3))) void*)(unsigned)(uintptr_t)l, 16, 0, 0);
}

DEV float wave_sum64(float v) {
#pragma unroll
  for (int off = 32; off > 0; off >>= 1) v += __shfl_down(v, off);
  return v;  // lane 0 holds sum
}

// ---------------- LN body (shared by prep & proj_reduce_ln) ----------------
DEV void ln_body(const float4 v, const float* g, const float* be, u16* out_row, int t,
                 float* red) {
  const int w = t >> 6, L = t & 63;
  float s = v.x + v.y + v.z + v.w;
  s = wave_sum64(s);
  if (L == 0) red[w] = s;
  __syncthreads();
  const float mean = (red[0] + red[1] + red[2] + red[3]) * (1.0f / 1024.0f);
  const float dx = v.x - mean, dy = v.y - mean, dz = v.z - mean, dw = v.w - mean;
  float q = dx * dx + dy * dy + dz * dz + dw * dw;
  q = wave_sum64(q);
  if (L == 0) red[4 + w] = q;
  __syncthreads();
  const float var = (red[4] + red[5] + red[6] + red[7]) * (1.0f / 1024.0f);
  const float rs = rsqrtf(var + 1e-5f);
  const float4 gg = reinterpret_cast<const float4*>(g)[t];
  const float4 bb = reinterpret_cast<const float4*>(be)[t];
  ushort4 o;
  o.x = f2bf(dx * rs * gg.x + bb.x);
  o.y = f2bf(dy * rs * gg.y + bb.y);
  o.z = f2bf(dz * rs * gg.z + bb.z);
  o.w = f2bf(dw * rs * gg.w + bb.w);
  reinterpret_cast<ushort4*>(out_row)[t] = o;
}

// ---- prep: ln1(x)->hbuf  +  4 weight transpose-converts, one launch ----
__global__ __launch_bounds__(256) void prep_kernel(
    const float* __restrict__ x, const float* __restrict__ ln1g,
    const float* __restrict__ ln1b, u16* __restrict__ hbuf,
    const float* __restrict__ Wqkv, u16* __restrict__ wt_qkv,
    const float* __restrict__ Wproj, u16* __restrict__ wt_proj,
    const float* __restrict__ Wfc, u16* __restrict__ wt_fc,
    const float* __restrict__ Wout, u16* __restrict__ wt_out) {
  __shared__ float smem[32 * 33];
  int id = blockIdx.x;
  const int t = threadIdx.x;
  if (id < 4096) {
    const float4 v = reinterpret_cast<const float4*>(x + (size_t)id * 1024)[t];
    ln_body(v, ln1g, ln1b, hbuf + (size_t)id * 1024, t, smem);
    return;
  }
  id -= 4096;
  const float* W;
  u16* Wt;
  int K, N, nbx;
  if (id < 3072) {
    W = Wqkv; Wt = wt_qkv; K = 1024; N = 3072; nbx = 96;
  } else if (id < 3072 + 1024) {
    id -= 3072; W = Wproj; Wt = wt_proj; K = 1024; N = 1024; nbx = 32;
  } else if (id < 3072 + 1024 + 4096) {
    id -= 3072 + 1024; W = Wfc; Wt = wt_fc; K = 1024; N = 4096; nbx = 128;
  } else {
    id -= 3072 + 1024 + 4096; W = Wout; Wt = wt_out; K = 4096; N = 1024; nbx = 32;
  }
  float(*tile)[33] = (float(*)[33])smem;
  const int c0 = (id % nbx) * 32, r0 = (id / nbx) * 32;
  const int tx = t & 31, ty = t >> 5;  // ty 0..7
#pragma unroll
  for (int j = 0; j < 4; ++j)
    tile[ty + j * 8][tx] = W[(size_t)(r0 + ty + j * 8) * N + c0 + tx];
  __syncthreads();
#pragma unroll
  for (int j = 0; j < 4; ++j) {
    const int n = c0 + ty + j * 8, k = r0 + tx;
    Wt[(size_t)n * K + k] = f2bf(tile[tx][ty + j * 8]);
  }
}

// ------- fused: x2 = x + bproj + P0 + P1 (bf16 partials); hbuf = LN(x2) bf16 -------
__global__ __launch_bounds__(256) void proj_reduce_ln(const float* __restrict__ x,
                                                      const float* __restrict__ bias,
                                                      const u16* __restrict__ P0,
                                                      const u16* __restrict__ P1,
                                                      const float* __restrict__ g,
                                                      const float* __restrict__ be,
                                                      float* __restrict__ x2,
                                                      u16* __restrict__ hbuf) {
  const int row = blockIdx.x, t = threadIdx.x;
  const size_t off = (size_t)row * 1024;
  __shared__ float red[8];
  const float4 xv = reinterpret_cast<const float4*>(x + off)[t];
  const float4 bv = reinterpret_cast<const float4*>(bias)[t];
  const ushort4 p0 = reinterpret_cast<const ushort4*>(P0 + off)[t];
  const ushort4 p1 = reinterpret_cast<const ushort4*>(P1 + off)[t];
  float4 v;
  v.x = xv.x + bv.x + bf2f(p0.x) + bf2f(p1.x);
  v.y = xv.y + bv.y + bf2f(p0.y) + bf2f(p1.y);
  v.z = xv.z + bv.z + bf2f(p0.z) + bf2f(p1.z);
  v.w = xv.w + bv.w + bf2f(p0.w) + bf2f(p1.w);
  reinterpret_cast<float4*>(x2 + off)[t] = v;
  ln_body(v, g, be, hbuf + off, t, red);
}

// ------- fused: d_out = x2 + bout + P0+P1 (bf16 partials, split-K=2) -------
__global__ __launch_bounds__(256) void out_reduce(const float* __restrict__ x2,
                                                  const float* __restrict__ bias,
                                                  const u16* __restrict__ P0,
                                                  const u16* __restrict__ P1,
                                                  float* __restrict__ dout) {
  const int row = blockIdx.x, t = threadIdx.x;
  const size_t off = (size_t)row * 1024;
  const float4 xv = reinterpret_cast<const float4*>(x2 + off)[t];
  const float4 bv = reinterpret_cast<const float4*>(bias)[t];
  const ushort4 a = reinterpret_cast<const ushort4*>(P0 + off)[t];
  const ushort4 b = reinterpret_cast<const ushort4*>(P1 + off)[t];
  float4 o;
  o.x = xv.x + bv.x + bf2f(a.x) + bf2f(b.x);
  o.y = xv.y + bv.y + bf2f(a.y) + bf2f(b.y);
  o.z = xv.z + bv.z + bf2f(a.z) + bf2f(b.z);
  o.w = xv.w + bv.w + bf2f(a.w) + bf2f(b.w);
  reinterpret_cast<float4*>(dout + off)[t] = o;
}

// ---------------- GEMM: C[M,N] = A[M,K](bf16) @ Bt[N,K]^T(bf16) + epilogue --------
// BK=64 (32 MFMA per barrier drain).  Logical tiles: (bm = m-tile, bn = n-tile,
// zz = K-slice), derived from a bijective remap of the linear block id:
//   1) XCD chunking: block lands on XCD (lin%8); give each XCD a CONTIGUOUS
//      tile range (requires total%8==0 — true for all launches here).
//   2) 8x8 grouped raster within the chunk: the ~64 blocks concurrently
//      resident per XCD then cover an 8m x 8n tile square -> working set
//      8*256KB(A) + 8*256KB(B) = 4MB = one XCD's L2.
// NOTE (R8): non-temporal epilogue stores REGRESSED (scalar strided u16 stores
// rely on L2 write-merge; nt bypassed it -> 1.8x HBM write amplification).
// F_PART4: bf16 partial at pp[z].  F_VT: blocks with n0>=2048 write C transposed
// into pp0 as V^T [b,h,d,s] (fuses the V-transpose into the qkv epilogue).
enum { F_BIAS = 1, F_RESID = 2, F_RELU = 4, F_BF16 = 8, F_PART4 = 32, F_VT = 64 };

template <int FLAGS>
__global__ __launch_bounds__(256, 2) void gemm_bt(const u16* __restrict__ A,
                                                  const u16* __restrict__ Bt,
                                                  const float* __restrict__ bias,
                                                  const float* __restrict__ resid,
                                                  void* __restrict__ Cout,
                                                  u16* __restrict__ pp0, u16* __restrict__ pp1,
                                                  u16* __restrict__ pp2, u16* __restrict__ pp3,
                                                  int M, int N, int K, int Kst) {
  __shared__ __attribute__((aligned(16))) u16 sA[2][128 * 32];
  __shared__ __attribute__((aligned(16))) u16 sB[2][128 * 32];

  // ---- block-id remap: XCD chunk + 8x8 grouped raster (bijective) ----
  const int gx = gridDim.x, gy = gridDim.y;
  const int tilesPerZ = gx * gy;
  int lin = (blockIdx.z * gy + blockIdx.y) * gx + blockIdx.x;
  const int total = tilesPerZ * gridDim.z;
  if (!(total & 7)) lin = (lin & 7) * (total >> 3) + (lin >> 3);
  const int zz = lin / tilesPerZ;
  const int pid = lin - zz * tilesPerZ;
  const int npg = gx << 3;  // tiles per 8-m-row group band
  const int gid = pid / npg;
  const int rem = pid - gid * npg;
  const int fm = gid << 3;
  const int gsm = (gy - fm < 8) ? (gy - fm) : 8;
  const int bm = fm + rem % gsm;
  const int bn = rem / gsm;

  const int t = threadIdx.x, w = t >> 6, L = t & 63, quad = L >> 4, l15 = L & 15;
  const int wm = w >> 1, wn = w & 1;
  const int m0 = bm * 128, n0 = bn * 128;
  const u16* Ag = A + (size_t)m0 * Kst + (size_t)zz * K;
  const u16* Bg = Bt + (size_t)n0 * Kst + (size_t)zz * K;

  f32x4 acc[4][4] = {};

  for (int k0 = 0; k0 < K; k0 += 64) {
    __syncthreads();
#pragma unroll
    for (int h = 0; h < 2; ++h) {
#pragma unroll
      for (int i = 0; i < 2; ++i) {
        const int cp = i * 256 + t, rr = cp >> 2, cc = (cp & 3) << 3;
        gl_lds16(Ag + (size_t)rr * Kst + k0 + h * 32 + cc, &sA[h][(i * 256 + w * 64) * 8]);
      }
#pragma unroll
      for (int i = 0; i < 2; ++i) {
        const int cp = i * 256 + t, rr = cp >> 2, cc = (cp & 3) << 3;
        gl_lds16(Bg + (size_t)rr * Kst + k0 + h * 32 + cc, &sB[h][(i * 256 + w * 64) * 8]);
      }
    }
    __syncthreads();

#pragma unroll
    for (int h = 0; h < 2; ++h) {
      bf16x8 af[4], bfr[4];
#pragma unroll
      for (int m = 0; m < 4; ++m)
        af[m] = *(const bf16x8*)&sA[h][(wm * 64 + m * 16 + l15) * 32 + quad * 8];
#pragma unroll
      for (int n = 0; n < 4; ++n)
        bfr[n] = *(const bf16x8*)&sB[h][(wn * 64 + n * 16 + l15) * 32 + quad * 8];
#pragma unroll
      for (int m = 0; m < 4; ++m)
#pragma unroll
        for (int n = 0; n < 4; ++n)
          acc[m][n] =
              __builtin_amdgcn_mfma_f32_16x16x32_bf16(af[m], bfr[n], acc[m][n], 0, 0, 0);
    }
  }

  if ((FLAGS & F_VT) && n0 >= 2048) {
    // V block of the qkv GEMM: write C transposed into pp0 = Vt [b,h,d,s] (bf16)
#pragma unroll
    for (int m = 0; m < 4; ++m) {
#pragma unroll
      for (int n = 0; n < 4; ++n) {
        const int col = n0 + wn * 64 + n * 16 + l15;
        const float bv = bias[col];
        const int hh = (col - 2048) >> 6, dd = col & 63;
        const int srow = m0 + wm * 64 + m * 16 + quad * 4;
        const int bb = srow >> 11, ss = srow & 2047;
        ushort4 tmp;
        tmp.x = f2bf(acc[m][n][0] + bv);
        tmp.y = f2bf(acc[m][n][1] + bv);
        tmp.z = f2bf(acc[m][n][2] + bv);
        tmp.w = f2bf(acc[m][n][3] + bv);
        *(ushort4*)(pp0 + ((size_t)((bb * 16 + hh) * 64 + dd)) * 2048 + ss) = tmp;
      }
    }
    return;
  }

  u16* pbase = nullptr;
  if (FLAGS & F_PART4)
    pbase = (zz == 0) ? pp0 : (zz == 1) ? pp1 : (zz == 2) ? pp2 : pp3;

#pragma unroll
  for (int m = 0; m < 4; ++m) {
#pragma unroll
    for (int n = 0; n < 4; ++n) {
      const int col = n0 + wn * 64 + n * 16 + l15;
      const float bv = (FLAGS & F_BIAS) ? bias[col] : 0.0f;
#pragma unroll
      for (int rr = 0; rr < 4; ++rr) {
        const int row = m0 + wm * 64 + m * 16 + quad * 4 + rr;
        if (FLAGS & F_PART4) {
          pbase[(size_t)row * N + col] = f2bf(acc[m][n][rr]);
        } else {
          float v = acc[m][n][rr] + bv;
          if (FLAGS & F_RESID) v += resid[(size_t)row * N + col];
          if (FLAGS & F_RELU) v = fmaxf(v, 0.0f);
          if (FLAGS & F_BF16)
            ((u16*)Cout)[(size_t)row * N + col] = f2bf(v);
          else
            ((float*)Cout)[(size_t)row * N + col] = v;
        }
      }
    }
  }
}

// ---------------- Flash attention (causal), bf16 MFMA, no-max softmax ----------------
// QBLK=128, 8 waves (512 threads) share each 64x64 K/V tile.  Split-KV (no-max
// softmax => partials exactly additive): qt>=8 splits into chunk0 = kv tiles
// [0,16) -> acc0, chunk1 = [16, 2qt+2) -> acc1; LPT order; separate combine
// dispatch (R5: fence-fused combine cost ~180us in L2 wb/inv on CDNA4).
// Staging: DOUBLE-buffered async global_load_lds with COUNTED vmcnt (R1's
// proven sync structure).  R1's dbuf lost occupancy (grid 1024 wanted 4/CU,
// LDS forced 3); the current grid is 768 = exactly 3/CU, and dbuf LDS = 52KB
// still fits 3/CU -> zero occupancy cost now.  Per tile: issue next tile's 2
// loads into buf^1, s_waitcnt vmcnt(2) (waits only the OLDEST 2 = cur's; next
// 2 stay in flight across the barrier), compute, lgkmcnt(0), barrier.  This
// removes the fully-exposed vmcnt(0) load stall (~200-400cy) at every tile.
// K/V LDS tiles keep the 16B-slot XOR swizzle (conflict-free fragment reads):
// linear global_load_lds dest + inverse-swizzled GLOBAL source + swizzled read.
__global__ __launch_bounds__(512) void flash_attn(const u16* __restrict__ qkv,
                                                  const u16* __restrict__ Vt,
                                                  u16* __restrict__ y,
                                                  float* __restrict__ acc0,
                                                  float* __restrict__ acc1,
                                                  float* __restrict__ lacc0,
                                                  float* __restrict__ lacc1) {
  constexpr int S = 2048, D3 = 3072, D = 1024;
  constexpr float Csc = 0.125f * 1.44269504088896f;  // scale * log2(e)
  __shared__ __attribute__((aligned(16))) u16 sK[2][64 * 64];     // swizzled [kv][k]
  __shared__ __attribute__((aligned(16))) u16 sV[2][64 * 64];     // swizzled [d][kv]
  __shared__ __attribute__((aligned(16))) u16 sP[8][2 * 16 * 40]; // per-wave, pad stride 40

  // LPT schedule: e = bid>>5 (0..23), bh = bid&31 spreads heads.
  //   e<8             : qt=8+e,  chunk0 (kv tiles [0,16)), 16 tiles     -> acc0
  //   e>=8, even e-8  : qt=7-j  single (tiles [0,2qt+2)), 16-2j tiles   -> y
  //   e>=8, odd  e-8  : qt=15-j chunk1 (tiles [16,2qt+2)), 16-2j tiles  -> acc1
  const int bid = blockIdx.x;
  const int bh = bid & 31;
  const int e = bid >> 5;
  int qt, it0, it1, part;  // part: 0 = direct y, 1 = acc0, 2 = acc1
  if (e < 8) {
    qt = 8 + e; it0 = 0; it1 = 16; part = 1;
  } else {
    const int j = (e - 8) >> 1;
    if (((e - 8) & 1) == 0) {
      qt = 7 - j; it0 = 0; it1 = 2 * qt + 2; part = 0;
    } else {
      qt = 15 - j; it0 = 16; it1 = 2 * qt + 2; part = 2;
    }
  }
  const int b = bh >> 4, h = bh & 15;
  const int q0 = qt * 128;

  const int t = threadIdx.x, w = t >> 6, L = t & 63, quad = L >> 4, l15 = L & 15;
  const int qw = q0 + w * 16;  // this wave's first q row

  const u16* qbase = qkv + (size_t)(b * S) * D3 + h * 64;
  const u16* Kbase = qbase + D;
  const u16* Vbase = Vt + (size_t)((b * 16 + h) * 64) * S;

  // staging coords (512 threads cover the 512 16B-slots of one 8KB tile):
  // slot p = t; row = p>>3, logical col block ks = (p&7) ^ (row&7)
  const int srow = t >> 3;
  const int k8 = ((t & 7) ^ (srow & 7)) << 3;
  const u16* Ksrc = Kbase + (size_t)srow * D3 + k8;  // + kv0*D3 per tile
  const u16* Vsrc = Vbase + (size_t)srow * S + k8;   // + kv0 per tile

  bf16x8 aQ[2];
#pragma unroll
  for (int kk = 0; kk < 2; ++kk)
    aQ[kk] = *(const bf16x8*)(qbase + (size_t)(qw + l15) * D3 + kk * 32 + quad * 8);

  bf16x8 ones;
#pragma unroll
  for (int i = 0; i < 8; ++i) ones[i] = (__bf16)1.0f;

  f32x4 acc[4] = {};
  f32x4 lacc = {};

  u16* sPw = sP[w];
  const int swz = l15 & 7;  // == row&7 for all fragment rows (row = n*16+l15)

  // prologue: stage first tile into buf 0 (2 vmem ops per thread)
  gl_lds16(Ksrc + (size_t)(it0 * 64) * D3, &sK[0][(w * 64) * 8]);
  gl_lds16(Vsrc + it0 * 64, &sV[0][(w * 64) * 8]);

  int cur = 0;
  for (int it = it0; it < it1; ++it) {
    const int kv0 = it * 64;
    if (it + 1 < it1) {
      // issue next tile's loads into the other buffer; wait only the oldest
      // 2 (cur's) -> next 2 remain in flight across the barrier and retire
      // under this tile's compute.  Write-after-read on buf^1 is protected
      // by the previous iteration's lgkmcnt(0)+barrier.
      const int kvn = kv0 + 64;
      gl_lds16(Ksrc + (size_t)kvn * D3, &sK[cur ^ 1][(w * 64) * 8]);
      gl_lds16(Vsrc + kvn, &sV[cur ^ 1][(w * 64) * 8]);
      asm volatile("s_waitcnt vmcnt(2)" ::: "memory");
    } else {
      asm volatile("s_waitcnt vmcnt(0)" ::: "memory");
    }
    __builtin_amdgcn_s_barrier();

    const u16* sKc = sK[cur];
    const u16* sVc = sV[cur];

    f32x4 s[4] = {};
    __builtin_amdgcn_s_setprio(1);
#pragma unroll
    for (int kk = 0; kk < 2; ++kk) {
#pragma unroll
      for (int n = 0; n < 4; ++n) {
        const bf16x8 bK =
            *(const bf16x8*)&sKc[(n * 16 + l15) * 64 + ((kk * 4 + quad) ^ swz) * 8];
        s[n] = __builtin_amdgcn_mfma_f32_16x16x32_bf16(aQ[kk], bK, s[n], 0, 0, 0);
      }
    }
    __builtin_amdgcn_s_setprio(0);

    if (kv0 + 63 > qw) {
#pragma unroll
      for (int n = 0; n < 4; ++n) {
        const int col = kv0 + n * 16 + l15;
#pragma unroll
        for (int r = 0; r < 4; ++r) {
          const int row = qw + quad * 4 + r;
          const float p = __builtin_amdgcn_exp2f(s[n][r] * Csc);
          s[n][r] = (col > row) ? 0.0f : p;
        }
      }
    } else {
#pragma unroll
      for (int n = 0; n < 4; ++n)
#pragma unroll
        for (int r = 0; r < 4; ++r) s[n][r] = __builtin_amdgcn_exp2f(s[n][r] * Csc);
    }

#pragma unroll
    for (int n = 0; n < 4; ++n)
#pragma unroll
      for (int r = 0; r < 4; ++r)
        sPw[(n >> 1) * 640 + (quad * 4 + r) * 40 + (n & 1) * 16 + l15] = f2bf(s[n][r]);

    __builtin_amdgcn_s_setprio(1);
#pragma unroll
    for (int kk = 0; kk < 2; ++kk) {
      const bf16x8 aP = *(const bf16x8*)&sPw[kk * 640 + l15 * 40 + quad * 8];
      lacc = __builtin_amdgcn_mfma_f32_16x16x32_bf16(aP, ones, lacc, 0, 0, 0);
#pragma unroll
      for (int dn = 0; dn < 4; ++dn) {
        const bf16x8 bV =
            *(const bf16x8*)&sVc[(dn * 16 + l15) * 64 + ((kk * 4 + quad) ^ swz) * 8];
        acc[dn] = __builtin_amdgcn_mfma_f32_16x16x32_bf16(aP, bV, acc[dn], 0, 0, 0);
      }
    }
    __builtin_amdgcn_s_setprio(0);

    // all waves' ds_reads from buf[cur] retired before next iter overwrites it
    asm volatile("s_waitcnt lgkmcnt(0)" ::: "memory");
    __builtin_amdgcn_s_barrier();
    cur ^= 1;
  }

  if (part == 0) {
#pragma unroll
    for (int r = 0; r < 4; ++r) {
      const float inv = 1.0f / lacc[r];
      const int row = qw + quad * 4 + r;
      u16* yb = y + (size_t)(b * S + row) * D + h * 64 + l15;
#pragma unroll
      for (int dn = 0; dn < 4; ++dn) yb[dn * 16] = f2bf(acc[dn][r] * inv);
    }
  } else {
    float* accP = (part == 1) ? acc0 : acc1;
    float* laccP = (part == 1) ? lacc0 : lacc1;
#pragma unroll
    for (int r = 0; r < 4; ++r) {
      const int row = qw + quad * 4 + r;
      const int g = (bh << 10) + (row - 1024);  // rows 1024..2047 only (qt>=8)
      float* ap = accP + (size_t)g * 64 + l15;
#pragma unroll
      for (int dn = 0; dn < 4; ++dn) ap[dn * 16] = acc[dn][r];
      if (l15 == 0) laccP[g] = lacc[r];
    }
  }
}

// ---- combine the two split-KV partials: y = (a0+a1)/(l0+l1), rows 1024..2047 ----
__global__ __launch_bounds__(256) void attn_combine(const float* __restrict__ acc0,
                                                    const float* __restrict__ acc1,
                                                    const float* __restrict__ lacc0,
                                                    const float* __restrict__ lacc1,
                                                    u16* __restrict__ y) {
  const int t = threadIdx.x;
  const int g = blockIdx.x * 4 + (t >> 6);  // 0..32767 (bh*1024 + ri)
  const int d = t & 63;
  const int bh = g >> 10, ri = g & 1023;
  const int b = bh >> 4, h = bh & 15;
  const int row = 1024 + ri;
  const size_t po = (size_t)g * 64 + d;
  const float l = lacc0[g] + lacc1[g];
  const float v = (acc0[po] + acc1[po]) / l;
  y[((size_t)(b * 2048 + row)) * 1024 + h * 64 + d] = f2bf(v);
}

// ---------------- host ----------------
extern "C" void kernel_launch(void* const* d_in, const int* in_sizes, int n_in,
                              void* d_out, int out_size, void* d_ws, size_t ws_size,
                              hipStream_t stream) {
  const float* x = (const float*)d_in[0];
  const float* ln1g = (const float*)d_in[1];
  const float* ln1b = (const float*)d_in[2];
  const float* ln2g = (const float*)d_in[3];
  const float* ln2b = (const float*)d_in[4];
  const float* Wqkv = (const float*)d_in[5];
  const float* bqkv = (const float*)d_in[6];
  const float* Wproj = (const float*)d_in[7];
  const float* bproj = (const float*)d_in[8];
  const float* Wfc = (const float*)d_in[9];
  const float* bfc = (const float*)d_in[10];
  const float* Wout = (const float*)d_in[11];
  const float* bout = (const float*)d_in[12];

  char* ws = (char*)d_ws;
  const size_t MB = 1u << 20;
  // Liveness-based layout; peak 88 MB.
  u16* wt_out = (u16*)(ws + 0 * MB);    //  0- 8  [until out gemm]
  u16* hbuf = (u16*)(ws + 8 * MB);      //  8-16  [ln1->qkv; ln2->fc]
  float* x2 = (float*)(ws + 16 * MB);   // 16-32  [proj_reduce -> out_reduce]
  u16* ybuf = (u16*)(ws + 32 * MB);     // 32-40  [flash -> proj gemm]
  u16* qkvb = (u16*)(ws + 40 * MB);     // 40-64  [qkv gemm -> flash] (Q,K only)
  u16* vtb = (u16*)(ws + 64 * MB);      // 64-72  [qkv gemm (V^T) -> flash]
  u16* wt_qkv = (u16*)(ws + 72 * MB);   // 72-78  [until qkv gemm]
  u16* wt_proj = (u16*)(ws + 78 * MB);  // 78-80  [until proj gemm]
  u16* wt_fc = (u16*)(ws + 80 * MB);    // 80-88  [until fc gemm]
  u16* projP0 = (u16*)(ws + 40 * MB);   // 40-48  bf16 proj partials (qkvb dead)
  u16* projP1 = (u16*)(ws + 48 * MB);   // 48-56
  u16* m1 = (u16*)(ws + 40 * MB);       // 40-72  fc out bf16 (projP dead)
  u16* po0 = (u16*)(ws + 8 * MB);       // hbuf dead after fc (split-K=2 partials)
  u16* po1 = (u16*)(ws + 32 * MB);      // ybuf dead after proj
  // split-KV partials, live only flash -> combine (hbuf/x2 contents dead then):
  float* facc0 = (float*)(ws + 8 * MB);   //  8-16  (hbuf region, dead during flash)
  float* facc1 = (float*)(ws + 16 * MB);  // 16-24  (x2 region, written later)
  float* flacc0 = (float*)(ws + 24 * MB); // 24-24.125
  float* flacc1 = (float*)(ws + 25 * MB); // 25-25.125

  // ln1 + all 4 weight transposes in one launch
  prep_kernel<<<4096 + 3072 + 1024 + 4096 + 4096, 256, 0, stream>>>(
      x, ln1g, ln1b, hbuf, Wqkv, wt_qkv, Wproj, wt_proj, Wfc, wt_fc, Wout, wt_out);

  // qkv GEMM; V-columns (n0>=2048) written transposed straight into vtb
  gemm_bt<F_BIAS | F_BF16 | F_VT><<<dim3(24, 32), 256, 0, stream>>>(
      hbuf, wt_qkv, bqkv, nullptr, qkvb, vtb, nullptr, nullptr, nullptr,
      4096, 3072, 1024, 1024);
  flash_attn<<<768, 512, 0, stream>>>(qkvb, vtb, ybuf, facc0, facc1, flacc0, flacc1);
  attn_combine<<<8192, 256, 0, stream>>>(facc0, facc1, flacc0, flacc1, ybuf);

  // proj: split-K=2 into bf16 partials, then fused residual+bias+LN2
  gemm_bt<F_PART4><<<dim3(8, 32, 2), 256, 0, stream>>>(
      ybuf, wt_proj, nullptr, nullptr, nullptr, projP0, projP1, nullptr, nullptr,
      4096, 1024, 512, 1024);
  proj_reduce_ln<<<4096, 256, 0, stream>>>(x, bproj, projP0, projP1, ln2g, ln2b, x2, hbuf);

  gemm_bt<F_BIAS | F_RELU | F_BF16><<<dim3(32, 32), 256, 0, stream>>>(
      hbuf, wt_fc, bfc, nullptr, m1, nullptr, nullptr, nullptr, nullptr,
      4096, 4096, 1024, 1024);

  // out: split-K=2 into bf16 partials, then fused residual+bias reduce
  gemm_bt<F_PART4><<<dim3(8, 32, 2), 256, 0, stream>>>(
      m1, wt_out, nullptr, nullptr, nullptr, po0, po1, nullptr, nullptr,
      4096, 1024, 2048, 4096);
  out_reduce<<<4096, 256, 0, stream>>>(x2, bout, po0, po1, (float*)d_out);
}